// Round 4
// baseline (126.980 us; speedup 1.0000x reference)
//
#include <hip/hip_runtime.h>
#include <hip/hip_cooperative_groups.h>

namespace cg = cooperative_groups;

// B=16384, IN=256, N=64, DEG=7 -> D=2048.
// Identity: out[b] = T[b] . (coeffs^T @ hw). Single cooperative kernel:
//   phase A (blocks 0..511, wave 0): one float4-column of w each (lane=neuron)
//   phase 0 (all): load x, stash tanh in registers   (overlaps phase A)
//   grid.sync()
//   phase 1 (all): per-lane w slice, Cheb recurrence dot, wave-reduce, store.
// R3 lesson: 2 separate dispatches left ~12us of per-dispatch/per-call overhead;
// kernels themselves total ~4-5us vs 2.8us memory floor.

constexpr int B_SAMPLES = 16384;
constexpr int IN_DIM    = 256;
constexpr int N_NEURONS = 64;
constexpr int DEGP1     = 8;
constexpr int D_FEAT    = IN_DIM * DEGP1;   // 2048
constexpr int D4        = D_FEAT / 4;       // 512 float4 columns of w
constexpr int SPB       = 16;               // samples per block
constexpr int GRID      = B_SAMPLES / SPB;  // 1024 = 4 blocks/CU, coop-resident

__device__ __forceinline__ float fast_tanh(float v) {
    // tanh(v) = 1 - 2/(e^{2v}+1); exact limits at +/-inf. absmax slack is huge.
    float e = __expf(2.0f * v);
    return 1.0f - 2.0f * __builtin_amdgcn_rcpf(e + 1.0f);
}

__global__ __launch_bounds__(256, 4) void kan_fused(
        const float* __restrict__ x, const float* __restrict__ coeffs,
        const float* __restrict__ hw, float* __restrict__ w,
        float* __restrict__ out) {
    const int tid  = threadIdx.x;
    const int lane = tid & 63;
    const int wv   = tid >> 6;                 // wave 0..3
    const int blk  = blockIdx.x;
    const int b0   = blk * SPB;

    // ---- Phase A: blocks 0..511, wave 0 only. d4-column = blk; lane = neuron.
    if (blk < D4 && wv == 0) {
        const float h = hw[lane];
        float4 c = reinterpret_cast<const float4*>(coeffs)[(size_t)lane * D4 + blk];
        c.x *= h; c.y *= h; c.z *= h; c.w *= h;
#pragma unroll
        for (int off = 32; off > 0; off >>= 1) {
            c.x += __shfl_down(c.x, off, 64);
            c.y += __shfl_down(c.y, off, 64);
            c.z += __shfl_down(c.z, off, 64);
            c.w += __shfl_down(c.w, off, 64);
        }
        if (lane == 0) reinterpret_cast<float4*>(w)[blk] = c;
    }

    // ---- Phase 0: all blocks. Wave wv owns samples b0+wv+4s; lane owns 4 dims.
    float t[16];
#pragma unroll
    for (int s = 0; s < 4; ++s) {
        const int b = b0 + wv + s * 4;
        float4 xv = reinterpret_cast<const float4*>(x + (size_t)b * IN_DIM)[lane];
        t[s * 4 + 0] = fast_tanh(xv.x);
        t[s * 4 + 1] = fast_tanh(xv.y);
        t[s * 4 + 2] = fast_tanh(xv.z);
        t[s * 4 + 3] = fast_tanh(xv.w);
    }

    __threadfence();            // make w writes device-visible before the barrier
    cg::this_grid().sync();

    // ---- Phase 1: per-lane weight slice w[lane*32 .. lane*32+31] (8 float4s).
    const float4* w4 = reinterpret_cast<const float4*>(w) + (size_t)lane * 8;
    float4 W[4][2];
#pragma unroll
    for (int j = 0; j < 4; ++j) { W[j][0] = w4[2 * j]; W[j][1] = w4[2 * j + 1]; }

#pragma unroll
    for (int s = 0; s < 4; ++s) {
        float acc = 0.f;
#pragma unroll
        for (int j = 0; j < 4; ++j) {
            const float tv = t[s * 4 + j];
            const float t2 = 2.f * tv;
            const float4 wlo = W[j][0], whi = W[j][1];
            float Tm2 = 1.f, Tm1 = tv, T;
            float a = fmaf(wlo.y, tv, wlo.x);                                // T0,T1
            T = t2 * Tm1 - Tm2; a = fmaf(wlo.z, T, a); Tm2 = Tm1; Tm1 = T;   // T2
            T = t2 * Tm1 - Tm2; a = fmaf(wlo.w, T, a); Tm2 = Tm1; Tm1 = T;   // T3
            T = t2 * Tm1 - Tm2; a = fmaf(whi.x, T, a); Tm2 = Tm1; Tm1 = T;   // T4
            T = t2 * Tm1 - Tm2; a = fmaf(whi.y, T, a); Tm2 = Tm1; Tm1 = T;   // T5
            T = t2 * Tm1 - Tm2; a = fmaf(whi.z, T, a); Tm2 = Tm1; Tm1 = T;   // T6
            T = t2 * Tm1 - Tm2; a = fmaf(whi.w, T, a);                       // T7
            acc += a;
        }
#pragma unroll
        for (int off = 32; off > 0; off >>= 1)
            acc += __shfl_down(acc, off, 64);
        if (lane == 0) out[b0 + wv + s * 4] = acc;
    }
}

extern "C" void kernel_launch(void* const* d_in, const int* in_sizes, int n_in,
                              void* d_out, int out_size, void* d_ws, size_t ws_size,
                              hipStream_t stream) {
    const float* x      = (const float*)d_in[0];   // [B, IN]
    const float* coeffs = (const float*)d_in[1];   // [N, D]
    const float* hw     = (const float*)d_in[2];   // [N]
    float* out = (float*)d_out;                    // [B]
    float* w   = (float*)d_ws;                     // 2048 floats scratch

    void* args[] = {(void*)&x, (void*)&coeffs, (void*)&hw, (void*)&w, (void*)&out};
    hipLaunchCooperativeKernel(reinterpret_cast<void*>(&kan_fused),
                               dim3(GRID), dim3(256), args, 0, stream);
}

// Round 5
// 16.949 us; speedup vs baseline: 7.4919x; 7.4919x over previous
//
#include <hip/hip_runtime.h>

// B=16384, IN=256, N=64, DEG=7 -> D=2048.
// Identity: out[b] = T[b] . (coeffs^T @ hw).
// R4 lesson: cooperative grid.sync costs ~120us on 8 XCDs -- never again.
// R3 lesson: two dependent dispatches carry ~10us of launch/serialization cost.
// => ONE plain kernel; each block redundantly computes w = coeffs^T@hw (512KB
//    coeffs is L2/L3-hot; 256 blocks * 512KB = 128MB L2 traffic ~3.7us, hidden
//    under the x stream by issuing x loads before the w loop).

constexpr int B_SAMPLES = 16384;
constexpr int IN_DIM    = 256;
constexpr int N_NEURONS = 64;
constexpr int DEGP1     = 8;
constexpr int D_FEAT    = IN_DIM * DEGP1;   // 2048
constexpr int D4        = D_FEAT / 4;       // 512 float4 columns of w
constexpr int TPB       = 1024;             // 16 waves
constexpr int SPB       = 64;               // samples per block
constexpr int GRID      = B_SAMPLES / SPB;  // 256 blocks = 1/CU

__device__ __forceinline__ float fast_tanh(float v) {
    // tanh(v) = 1 - 2/(e^{2v}+1); exact limits at +/-inf. Accuracy slack is huge.
    float e = __expf(2.0f * v);
    return 1.0f - 2.0f * __builtin_amdgcn_rcpf(e + 1.0f);
}

__global__ __launch_bounds__(TPB, 1) void kan_fused(
        const float* __restrict__ x, const float* __restrict__ coeffs,
        const float* __restrict__ hw, float* __restrict__ out) {
    const int tid  = threadIdx.x;
    const int lane = tid & 63;
    const int wv   = tid >> 6;                  // wave 0..15
    const int b0   = blockIdx.x * SPB;

    // ---- Issue this thread's x loads FIRST so HBM latency hides under phase A.
    // Wave wv owns samples b0+4*wv .. b0+4*wv+3; lane owns dims 4*lane..4*lane+3.
    float4 xv[4];
#pragma unroll
    for (int s = 0; s < 4; ++s) {
        const int b = b0 + wv * 4 + s;
        xv[s] = reinterpret_cast<const float4*>(x + (size_t)b * IN_DIM)[lane];
    }

    // ---- Phase A: per-block w = coeffs^T @ hw.
    // Thread owns d4 column (tid&511), neuron half (tid>>9): 32-neuron partial.
    const int d4   = tid & (D4 - 1);
    const int half = tid >> 9;
    const float4* c4 = reinterpret_cast<const float4*>(coeffs);
    float4 acc = {0.f, 0.f, 0.f, 0.f};
#pragma unroll
    for (int j = 0; j < 32; ++j) {
        const int n = half * 32 + j;
        const float h  = hw[n];
        const float4 c = c4[(size_t)n * D4 + d4];
        acc.x = fmaf(c.x, h, acc.x);
        acc.y = fmaf(c.y, h, acc.y);
        acc.z = fmaf(c.z, h, acc.z);
        acc.w = fmaf(c.w, h, acc.w);
    }

    __shared__ float4 wpart[2][D4];             // 16 KiB
    wpart[half][d4] = acc;
    __syncthreads();
    if (tid < D4) {
        float4 a = wpart[0][tid], b = wpart[1][tid];
        a.x += b.x; a.y += b.y; a.z += b.z; a.w += b.w;
        wpart[0][tid] = a;
    }
    __syncthreads();

    // ---- Phase B: per-lane weight slice (w[lane*32 .. +31] = 2 float4-pairs x4 dims).
    float4 W[4][2];
#pragma unroll
    for (int j = 0; j < 4; ++j) {
        W[j][0] = wpart[0][lane * 8 + 2 * j];
        W[j][1] = wpart[0][lane * 8 + 2 * j + 1];
    }

#pragma unroll
    for (int s = 0; s < 4; ++s) {
        const float xs[4] = {xv[s].x, xv[s].y, xv[s].z, xv[s].w};
        float accb = 0.f;
#pragma unroll
        for (int j = 0; j < 4; ++j) {
            const float t  = fast_tanh(xs[j]);
            const float t2 = 2.f * t;
            const float4 wlo = W[j][0], whi = W[j][1];
            float Tm2 = 1.f, Tm1 = t, T;
            float a = fmaf(wlo.y, t, wlo.x);                                // T0,T1
            T = t2 * Tm1 - Tm2; a = fmaf(wlo.z, T, a); Tm2 = Tm1; Tm1 = T;  // T2
            T = t2 * Tm1 - Tm2; a = fmaf(wlo.w, T, a); Tm2 = Tm1; Tm1 = T;  // T3
            T = t2 * Tm1 - Tm2; a = fmaf(whi.x, T, a); Tm2 = Tm1; Tm1 = T;  // T4
            T = t2 * Tm1 - Tm2; a = fmaf(whi.y, T, a); Tm2 = Tm1; Tm1 = T;  // T5
            T = t2 * Tm1 - Tm2; a = fmaf(whi.z, T, a); Tm2 = Tm1; Tm1 = T;  // T6
            T = t2 * Tm1 - Tm2; a = fmaf(whi.w, T, a);                      // T7
            accb += a;
        }
#pragma unroll
        for (int off = 32; off > 0; off >>= 1)
            accb += __shfl_down(accb, off, 64);
        if (lane == 0) out[b0 + wv * 4 + s] = accb;
    }
}

extern "C" void kernel_launch(void* const* d_in, const int* in_sizes, int n_in,
                              void* d_out, int out_size, void* d_ws, size_t ws_size,
                              hipStream_t stream) {
    const float* x      = (const float*)d_in[0];   // [B, IN]
    const float* coeffs = (const float*)d_in[1];   // [N, D]
    const float* hw     = (const float*)d_in[2];   // [N]
    float* out = (float*)d_out;                    // [B]

    kan_fused<<<GRID, TPB, 0, stream>>>(x, coeffs, hw, out);
}